// Round 8
// baseline (56.321 us; speedup 1.0000x reference)
//
#include <hip/hip_runtime.h>
#include <hip/hip_bf16.h>
#include <stdint.h>

// Problem constants
#define B_DIM 8
#define T_DIM 2048
#define INNER 256      // IN_DIM == HEAD_TOTAL == 256
#define NEGV (-1e9f)
#define SCALE 0.0625f  // 1/sqrt(256)

typedef __bf16 bf16_t;
typedef __bf16 bf16x8 __attribute__((ext_vector_type(8)));
typedef float f32x4 __attribute__((ext_vector_type(4)));

// ---- async global->LDS, 16B per lane (global_load_lds_dwordx4) ----
__device__ inline void gload_lds16(const bf16_t* g, bf16_t* lds) {
  __builtin_amdgcn_global_load_lds(
      (__attribute__((address_space(1))) void*)(g),
      (__attribute__((address_space(3))) void*)(lds),
      16, 0, 0);
}

// Stage a ROWSx64 bf16 tile into lds[ROWS][64] with 512 threads (8 waves).
// Linear LDS layout; wave-uniform LDS base + lane*16 (HW requirement).
template <int ROWS>
__device__ inline void stage_tile512(const bf16_t* gbase, int ldg,
                                     bf16_t (*lds)[64], int tid) {
  const int l = tid & 63;
  const int w = tid >> 6;        // 0..7
  const int sub = l >> 3;        // row within 8-row chunk
  const int ce = (l & 7) * 8;    // starting column element (8 bf16 = 16B)
#pragma unroll
  for (int i = 0; i < ROWS / 64; ++i) {
    const int chunk = i * 8 + w;               // uniform per wave
    const int row = chunk * 8 + sub;
    gload_lds16(gbase + (size_t)row * ldg + ce, &lds[chunk * 8][0]);
  }
}

// Stage a 128x64 tile from FP32 global into bf16 LDS (reg-staged convert),
// 256 threads. Issue all 8 global loads first, then cvt + ds_write.
__device__ inline void stage_tile_cvt(const float* gbase, int ldg,
                                      bf16_t (*lds)[64], int tid) {
  const int l = tid & 63;
  const int w = tid >> 6;
  const int sub = l >> 3;
  const int ce = (l & 7) * 8;
  f32x4 v[4][2];
#pragma unroll
  for (int i = 0; i < 4; ++i) {
    const int row = (i * 4 + w) * 8 + sub;
    const float* p = gbase + (size_t)row * ldg + ce;
    v[i][0] = *(const f32x4*)p;
    v[i][1] = *(const f32x4*)(p + 4);
  }
#pragma unroll
  for (int i = 0; i < 4; ++i) {
    const int row = (i * 4 + w) * 8 + sub;
    bf16x8 o;
#pragma unroll
    for (int j = 0; j < 4; ++j) {
      o[j]     = (bf16_t)v[i][0][j];
      o[4 + j] = (bf16_t)v[i][1][j];
    }
    *(bf16x8*)&lds[row][ce] = o;
  }
}

// ---- Kernel 1: Q = x @ Wq^T, K = x @ Wk^T, reading FP32 inputs directly ----
// fp32->bf16 conversion fused into the staging path. 256 threads, 128x128
// tile, m97 single-buffered structure (round-7 verified).
__global__ __launch_bounds__(256) void proj_kernel(
    const float* __restrict__ x, const float* __restrict__ Wq,
    const float* __restrict__ Wk, bf16_t* __restrict__ Q,
    bf16_t* __restrict__ Kout) {
  __shared__ bf16_t Al[128][64];
  __shared__ bf16_t Bl[128][64];
  const int tid = threadIdx.x;
  const int mrow = blockIdx.x * 128;   // row in [0, B*T)
  const int ncol = blockIdx.y * 128;   // out-feature
  const float* W = blockIdx.z ? Wk : Wq;
  bf16_t* O = blockIdx.z ? Kout : Q;

  const int l = tid & 63, wid = tid >> 6, wr = wid >> 1, wc = wid & 1;
  const int lr = l & 15, kg = l >> 4;

  f32x4 acc[4][4] = {};
  const float* Ax = x + (size_t)mrow * INNER;
  const float* Bw = W + (size_t)ncol * INNER;
#pragma unroll
  for (int k0 = 0; k0 < INNER; k0 += 64) {
    stage_tile_cvt(Ax + k0, INNER, Al, tid);
    stage_tile_cvt(Bw + k0, INNER, Bl, tid);
    __syncthreads();
#pragma unroll
    for (int kk = 0; kk < 2; ++kk) {
      bf16x8 af[4], bfm[4];
#pragma unroll
      for (int f = 0; f < 4; ++f) {
        af[f]  = *(const bf16x8*)&Al[wr * 64 + f * 16 + lr][kk * 32 + kg * 8];
        bfm[f] = *(const bf16x8*)&Bl[wc * 64 + f * 16 + lr][kk * 32 + kg * 8];
      }
#pragma unroll
      for (int m = 0; m < 4; ++m)
#pragma unroll
        for (int n = 0; n < 4; ++n)
          acc[m][n] = __builtin_amdgcn_mfma_f32_16x16x32_bf16(
              af[m], bfm[n], acc[m][n], 0, 0, 0);
    }
    __syncthreads();
  }

#pragma unroll
  for (int m = 0; m < 4; ++m)
#pragma unroll
    for (int n = 0; n < 4; ++n)
#pragma unroll
      for (int j = 0; j < 4; ++j) {
        // C/D layout: col = lane&15, row = (lane>>4)*4 + reg  [m89]
        int r = mrow + wr * 64 + m * 16 + kg * 4 + j;
        int c = ncol + wc * 64 + n * 16 + lr;
        O[(size_t)r * INNER + c] = (bf16_t)acc[m][n][j];
      }
}

// ---- Kernel 2: E = Q @ K^T * scale (+ mask); 128x256 tiles, 8 waves ----
// Widened col-tile (256): halves L2 tile-read traffic and barrier count per
// output byte vs 128x128 [round-8 lever]. 512 threads = 8 waves in 2x4;
// each wave owns a 64x64 sub-tile (4x4 frags, same 64-VGPR acc as before).
// XCD swizzle: `b = bid & 7` pins each batch's tiles to one XCD (Q_b + K_b
// = 2 MB fits the 4 MiB per-XCD L2). Lower tiles (scol+256 <= trow) fill
// -1e9 here so fill writes overlap compute blocks' stage/MFMA phases.
__global__ __launch_bounds__(512) void scores_kernel(
    const bf16_t* __restrict__ Q, const bf16_t* __restrict__ Kin,
    float* __restrict__ E) {
  const int bid = blockIdx.x;
  const int b = bid & 7;       // batch == XCD
  const int lid = bid >> 3;    // 0..127 tile id within batch
  const int rt = lid >> 3;     // row tile (t), 128-granular: 0..15
  const int ct = lid & 7;      // col tile (s), 256-granular: 0..7
  const int tid = threadIdx.x;
  float* Eb = E + (size_t)b * T_DIM * T_DIM;
  const int trow = rt * 128, scol = ct * 256;

  if (scol + 256 <= trow) {
    // tile entirely below diagonal: exact -1e9 fill (1KB row segments)
    const f32x4 neg = {NEGV, NEGV, NEGV, NEGV};
#pragma unroll
    for (int it = 0; it < 16; ++it) {
      int idx = it * 512 + tid;          // 0..8191 float4 slots
      int r = idx >> 6, c4 = idx & 63;
      *(f32x4*)&Eb[(size_t)(trow + r) * T_DIM + scol + c4 * 4] = neg;
    }
    return;
  }

  __shared__ bf16_t Al[128][64];   // Q rows
  __shared__ bf16_t Bl[256][64];   // K rows (widened)
  const int l = tid & 63;
  const int w = tid >> 6;          // wave 0..7
  const int wr = w >> 2, wc = w & 3;
  const int lr = l & 15, kg = l >> 4;

  f32x4 acc[4][4] = {};
  const bf16_t* Qb = Q + ((size_t)b * T_DIM + trow) * INNER;
  const bf16_t* Kb = Kin + ((size_t)b * T_DIM + scol) * INNER;
#pragma unroll
  for (int k0 = 0; k0 < INNER; k0 += 64) {
    stage_tile512<128>(Qb + k0, INNER, Al, tid);
    stage_tile512<256>(Kb + k0, INNER, Bl, tid);
    __syncthreads();   // compiler drains vmcnt(0) before s_barrier
#pragma unroll
    for (int kk = 0; kk < 2; ++kk) {
      bf16x8 af[4], bfm[4];
#pragma unroll
      for (int f = 0; f < 4; ++f) {
        af[f]  = *(const bf16x8*)&Al[wr * 64 + f * 16 + lr][kk * 32 + kg * 8];
        bfm[f] = *(const bf16x8*)&Bl[wc * 64 + f * 16 + lr][kk * 32 + kg * 8];
      }
#pragma unroll
      for (int m = 0; m < 4; ++m)
#pragma unroll
        for (int n = 0; n < 4; ++n)
          acc[m][n] = __builtin_amdgcn_mfma_f32_16x16x32_bf16(
              af[m], bfm[n], acc[m][n], 0, 0, 0);
    }
    __syncthreads();
  }

  const bool maskable = (scol < trow + 128);  // tile touches the diagonal
#pragma unroll
  for (int m = 0; m < 4; ++m)
#pragma unroll
    for (int n = 0; n < 4; ++n)
#pragma unroll
      for (int j = 0; j < 4; ++j) {
        int t = trow + wr * 64 + m * 16 + kg * 4 + j;
        int s = scol + wc * 64 + n * 16 + lr;
        float v = acc[m][n][j] * SCALE;
        if (maskable && s < t) v += NEGV;
        Eb[(size_t)t * T_DIM + s] = v;
      }
}

extern "C" void kernel_launch(void* const* d_in, const int* in_sizes, int n_in,
                              void* d_out, int out_size, void* d_ws,
                              size_t ws_size, hipStream_t stream) {
  const float* x  = (const float*)d_in[0];   // [8,2048,256] fp32
  const float* Wq = (const float*)d_in[1];   // [256,256] fp32
  const float* Wk = (const float*)d_in[2];   // [256,256] fp32
  float* out = (float*)d_out;

  const size_t n_x = (size_t)B_DIM * T_DIM * INNER;  // 4,194,304

  // Workspace layout (bf16): Q | K  (16.8 MB)
  bf16_t* Q = (bf16_t*)d_ws;
  bf16_t* K = Q + n_x;

  dim3 g1(B_DIM * T_DIM / 128, INNER / 128, 2);  // (128, 2, 2) = 512 blocks
  proj_kernel<<<g1, dim3(256), 0, stream>>>(x, Wq, Wk, Q, K);

  // 8 batches x (16 rt x 8 ct) = 1024 blocks
  scores_kernel<<<1024, 512, 0, stream>>>(Q, K, out);
}

// Round 9
// 53.765 us; speedup vs baseline: 1.0476x; 1.0476x over previous
//
#include <hip/hip_runtime.h>
#include <hip/hip_bf16.h>
#include <stdint.h>
#include <math.h>

// Problem constants
#define B_DIM 8
#define T_DIM 2048
#define INNER 256      // IN_DIM == HEAD_TOTAL == 256
#define NEGV (-1e9f)
#define SCALE 0.0625f  // 1/sqrt(256)

typedef __bf16 bf16_t;
typedef __bf16 bf16x8 __attribute__((ext_vector_type(8)));
typedef float f32x4 __attribute__((ext_vector_type(4)));

// ---- async global->LDS, 16B per lane (global_load_lds_dwordx4) ----
__device__ inline void gload_lds16(const bf16_t* g, bf16_t* lds) {
  __builtin_amdgcn_global_load_lds(
      (__attribute__((address_space(1))) void*)(g),
      (__attribute__((address_space(3))) void*)(lds),
      16, 0, 0);
}

// Stage a 128x64 bf16 tile (row stride ldg elements) into lds[128][64].
// Linear LDS layout; wave-uniform LDS base + lane*16 (HW requirement).
__device__ inline void stage_tile(const bf16_t* gbase, int ldg,
                                  bf16_t (*lds)[64], int tid) {
  const int l = tid & 63;
  const int w = tid >> 6;
  const int sub = l >> 3;        // row within 8-row chunk
  const int ce = (l & 7) * 8;    // starting column element (8 bf16 = 16B)
#pragma unroll
  for (int i = 0; i < 4; ++i) {
    const int chunk = i * 4 + w;               // 0..15, uniform per wave
    const int row = chunk * 8 + sub;
    gload_lds16(gbase + (size_t)row * ldg + ce, &lds[chunk * 8][0]);
  }
}

// Stage a 128x64 tile from FP32 global into bf16 LDS (reg-staged convert),
// 256 threads. Issue all 8 global loads first, then cvt + ds_write.
__device__ inline void stage_tile_cvt(const float* gbase, int ldg,
                                      bf16_t (*lds)[64], int tid) {
  const int l = tid & 63;
  const int w = tid >> 6;
  const int sub = l >> 3;
  const int ce = (l & 7) * 8;
  f32x4 v[4][2];
#pragma unroll
  for (int i = 0; i < 4; ++i) {
    const int row = (i * 4 + w) * 8 + sub;
    const float* p = gbase + (size_t)row * ldg + ce;
    v[i][0] = *(const f32x4*)p;
    v[i][1] = *(const f32x4*)(p + 4);
  }
#pragma unroll
  for (int i = 0; i < 4; ++i) {
    const int row = (i * 4 + w) * 8 + sub;
    bf16x8 o;
#pragma unroll
    for (int j = 0; j < 4; ++j) {
      o[j]     = (bf16_t)v[i][0][j];
      o[4 + j] = (bf16_t)v[i][1][j];
    }
    *(bf16x8*)&lds[row][ce] = o;
  }
}

// 128x128 output tile GEMM, C = A * B^T, both A and Bm are [row][k] bf16.
// Single-buffered m97 structure (32KB LDS -> 5 blocks/CU; rounds 3 & 8 show
// both dbuf and wider tiles regress this shape).
template <int KDIM>
__device__ inline void gemm_bt_128(const bf16_t* A, const bf16_t* Bm, int ld,
                                   bf16_t (*Al)[64], bf16_t (*Bl)[64],
                                   f32x4 acc[4][4], int tid) {
  const int l = tid & 63;
  const int wid = tid >> 6;
  const int wr = wid >> 1, wc = wid & 1;
  const int lr = l & 15;   // fragment row (A) / col (B) lane
  const int kg = l >> 4;   // k-chunk group 0..3
#pragma unroll
  for (int k0 = 0; k0 < KDIM; k0 += 64) {
    stage_tile(A + k0, ld, Al, tid);
    stage_tile(Bm + k0, ld, Bl, tid);
    __syncthreads();   // compiler drains vmcnt(0) before s_barrier
#pragma unroll
    for (int kk = 0; kk < 2; ++kk) {
      bf16x8 af[4], bfm[4];
#pragma unroll
      for (int f = 0; f < 4; ++f) {
        af[f]  = *(const bf16x8*)&Al[wr * 64 + f * 16 + lr][kk * 32 + kg * 8];
        bfm[f] = *(const bf16x8*)&Bl[wc * 64 + f * 16 + lr][kk * 32 + kg * 8];
      }
#pragma unroll
      for (int m = 0; m < 4; ++m)
#pragma unroll
        for (int n = 0; n < 4; ++n)
          acc[m][n] = __builtin_amdgcn_mfma_f32_16x16x32_bf16(
              af[m], bfm[n], acc[m][n], 0, 0, 0);
    }
    __syncthreads();
  }
}

// ---- Kernel 1: proj (Q = x@Wq^T, K = x@Wk^T, fp32 in, bf16 out) + the
// lower-triangle -1e9 fill of E, interleaved in one dispatch.
// Rationale: proj compute is read-bound (67MB HBM + L3 re-reads) with an
// idle write pipe; the 63MB fill saturates it. Scores then writes only its
// own 71MB of compute tiles against an uncontended pipe.
// Grid: 1472 blocks. Odd bid < 1024 -> compute (512); else fill (960).
__global__ __launch_bounds__(256) void proj_fill_kernel(
    const float* __restrict__ x, const float* __restrict__ Wq,
    const float* __restrict__ Wk, bf16_t* __restrict__ Q,
    bf16_t* __restrict__ Kout, float* __restrict__ E) {
  const int bid = blockIdx.x;
  const int tid = threadIdx.x;

  const bool is_compute = (bid < 1024) && (bid & 1);
  if (!is_compute) {
    // ---- fill block: one 128x128 tile strictly below the diagonal ----
    int fidx = (bid < 1024) ? (bid >> 1) : (bid - 512);   // 0..959
    const int b = fidx / 120;
    int r = fidx - b * 120;                               // 0..119
    // triangular decode: rt in [1,15], ct in [0,rt)
    int rt = (int)((1.0f + sqrtf(1.0f + 8.0f * (float)r)) * 0.5f);
    int ct = r - ((rt * (rt - 1)) >> 1);
    if (ct >= rt) { ct -= rt; rt += 1; }                  // fp-sqrt guard
    else if (ct < 0) { rt -= 1; ct = r - ((rt * (rt - 1)) >> 1); }
    float* Eb = E + (size_t)b * T_DIM * T_DIM;
    const int trow = rt * 128, scol = ct * 128;
    const f32x4 neg = {NEGV, NEGV, NEGV, NEGV};
#pragma unroll
    for (int it = 0; it < 16; ++it) {
      int idx = it * 256 + tid;          // 0..4095 float4 slots
      int rr = idx >> 5, c4 = idx & 31;
      *(f32x4*)&Eb[(size_t)(trow + rr) * T_DIM + scol + c4 * 4] = neg;
    }
    return;
  }

  // ---- compute block: one 128x128 tile of Q or K ----
  const int idx = bid >> 1;            // 0..511
  const int mrow = (idx & 127) * 128;  // row in [0, B*T)
  const int ncol = ((idx >> 7) & 1) * 128;
  const int z = idx >> 8;
  const float* W = z ? Wk : Wq;
  bf16_t* O = z ? Kout : Q;

  __shared__ bf16_t Al[128][64];
  __shared__ bf16_t Bl[128][64];
  const int l = tid & 63, wid = tid >> 6, wr = wid >> 1, wc = wid & 1;
  const int lr = l & 15, kg = l >> 4;

  f32x4 acc[4][4] = {};
  const float* Ax = x + (size_t)mrow * INNER;
  const float* Bw = W + (size_t)ncol * INNER;
#pragma unroll
  for (int k0 = 0; k0 < INNER; k0 += 64) {
    stage_tile_cvt(Ax + k0, INNER, Al, tid);
    stage_tile_cvt(Bw + k0, INNER, Bl, tid);
    __syncthreads();
#pragma unroll
    for (int kk = 0; kk < 2; ++kk) {
      bf16x8 af[4], bfm[4];
#pragma unroll
      for (int f = 0; f < 4; ++f) {
        af[f]  = *(const bf16x8*)&Al[wr * 64 + f * 16 + lr][kk * 32 + kg * 8];
        bfm[f] = *(const bf16x8*)&Bl[wc * 64 + f * 16 + lr][kk * 32 + kg * 8];
      }
#pragma unroll
      for (int m = 0; m < 4; ++m)
#pragma unroll
        for (int n = 0; n < 4; ++n)
          acc[m][n] = __builtin_amdgcn_mfma_f32_16x16x32_bf16(
              af[m], bfm[n], acc[m][n], 0, 0, 0);
    }
    __syncthreads();
  }

#pragma unroll
  for (int m = 0; m < 4; ++m)
#pragma unroll
    for (int n = 0; n < 4; ++n)
#pragma unroll
      for (int j = 0; j < 4; ++j) {
        // C/D layout: col = lane&15, row = (lane>>4)*4 + reg  [m89]
        int rr = mrow + wr * 64 + m * 16 + kg * 4 + j;
        int cc = ncol + wc * 64 + n * 16 + lr;
        O[(size_t)rr * INNER + cc] = (bf16_t)acc[m][n][j];
      }
}

// ---- Kernel 2: E = Q @ K^T * scale (+ diag mask), compute tiles only ----
// 1-D grid, 2048 blocks. XCD swizzle: `b = bid & 7` pins each batch's tiles
// to one XCD (Q_b + K_b = 2 MB fits the 4 MiB per-XCD L2). Lower tiles were
// filled by proj_fill_kernel. Scalar fragment stores (round-6: L2 aggregates
// 64B segments; LDS-transpose epilogue costs more than it saves).
__global__ __launch_bounds__(256) void scores_kernel(
    const bf16_t* __restrict__ Q, const bf16_t* __restrict__ Kin,
    float* __restrict__ E) {
  const int bid = blockIdx.x;
  const int b = bid & 7;       // batch == XCD
  const int lid = bid >> 3;    // 0..255 tile id within batch
  const int rt = lid >> 4;     // row tile (t)
  const int ct = lid & 15;     // col tile (s)
  if (ct < rt) return;         // lower tiles already filled
  const int tid = threadIdx.x;
  float* Eb = E + (size_t)b * T_DIM * T_DIM;
  const int trow = rt * 128, scol = ct * 128;

  __shared__ bf16_t Al[128][64];
  __shared__ bf16_t Bl[128][64];
  f32x4 acc[4][4] = {};
  const bf16_t* Qb = Q + (size_t)b * T_DIM * INNER;
  const bf16_t* Kb = Kin + (size_t)b * T_DIM * INNER;
  gemm_bt_128<INNER>(Qb + (size_t)trow * INNER, Kb + (size_t)scol * INNER,
                     INNER, Al, Bl, acc, tid);

  const int l = tid & 63, wid = tid >> 6, wr = wid >> 1, wc = wid & 1;
  const int lr = l & 15, kg = l >> 4;
  const bool diag = (ct == rt);
#pragma unroll
  for (int m = 0; m < 4; ++m)
#pragma unroll
    for (int n = 0; n < 4; ++n)
#pragma unroll
      for (int j = 0; j < 4; ++j) {
        int t = trow + wr * 64 + m * 16 + kg * 4 + j;
        int s = scol + wc * 64 + n * 16 + lr;
        float v = acc[m][n][j] * SCALE;
        if (diag && s < t) v += NEGV;
        Eb[(size_t)t * T_DIM + s] = v;
      }
}

extern "C" void kernel_launch(void* const* d_in, const int* in_sizes, int n_in,
                              void* d_out, int out_size, void* d_ws,
                              size_t ws_size, hipStream_t stream) {
  const float* x  = (const float*)d_in[0];   // [8,2048,256] fp32
  const float* Wq = (const float*)d_in[1];   // [256,256] fp32
  const float* Wk = (const float*)d_in[2];   // [256,256] fp32
  float* out = (float*)d_out;

  const size_t n_x = (size_t)B_DIM * T_DIM * INNER;  // 4,194,304

  // Workspace layout (bf16): Q | K  (16.8 MB)
  bf16_t* Q = (bf16_t*)d_ws;
  bf16_t* K = Q + n_x;

  // 512 proj-compute blocks + 960 fill blocks, interleaved
  proj_fill_kernel<<<1472, 256, 0, stream>>>(x, Wq, Wk, Q, K, out);

  scores_kernel<<<2048, 256, 0, stream>>>(Q, K, out);
}